// Round 1
// baseline (514.809 us; speedup 1.0000x reference)
//
#include <hip/hip_runtime.h>

#define Bc 512
#define Lc 512
#define Tc 128

// raw barrier: drain LDS ops, do NOT drain vmcnt (global prefetches stay in flight)
__device__ __forceinline__ void bar_lgkm() {
  asm volatile("s_waitcnt lgkmcnt(0)\n\ts_barrier" ::: "memory");
}

__global__ __launch_bounds__(128, 1)
void crf_forward(const float* __restrict__ x,      // [B,L,T]
                 const float* __restrict__ trans,  // [T,T]
                 const float* __restrict__ startT, // [T]
                 const float* __restrict__ endT,   // [T]
                 const int*   __restrict__ labels, // [B,L]
                 const int*   __restrict__ mask,   // [B,L]
                 float* __restrict__ diff_out,     // [B] logZ - score
                 float* __restrict__ msum_out)     // [B] per-batch mask sum
{
  __shared__ __align__(16) float p[Tc];
  __shared__ float sred[128];
  __shared__ int   mask_s[Lc];
  __shared__ float mslot;     // published shift value (alpha[0])
  __shared__ float s_score;
  __shared__ int   s_msum;

  const int j = threadIdx.x;        // 0..127 (tag column)
  const int b = blockIdx.x;         // batch
  const int lane = j & 63;
  const int wid  = j >> 6;
  const float* xb = x + (size_t)b * (Lc * Tc);
  const int* lb = labels + b * Lc;
  const int* mk = mask   + b * Lc;

  // ---- stage mask row into LDS ----
  for (int t = j; t < Lc; t += 128) mask_s[t] = mk[t];

  // ---- E column j in registers: ecol[i] = exp(trans[i][j]) ----
  float4 ecol[Tc / 4];
#pragma unroll
  for (int i = 0; i < Tc / 4; ++i) {
    ecol[i].x = __expf(trans[(4 * i + 0) * Tc + j]);
    ecol[i].y = __expf(trans[(4 * i + 1) * Tc + j]);
    ecol[i].z = __expf(trans[(4 * i + 2) * Tc + j]);
    ecol[i].w = __expf(trans[(4 * i + 3) * Tc + j]);
  }
  __syncthreads();

  // ---- mask sum (for last_idx and final normalization) ----
  int mpart = 0;
  for (int t = j; t < Lc; t += 128) mpart += mask_s[t];
  sred[j] = (float)mpart;
  __syncthreads();
#pragma unroll
  for (int s = 64; s > 0; s >>= 1) {
    if (j < s) sred[j] += sred[j + s];
    __syncthreads();
  }
  if (j == 0) s_msum = (int)sred[0];
  __syncthreads();
  const int msum = s_msum;

  // ---- gold-path score ----
  float spart = 0.f;
  for (int t = j; t < Lc - 1; t += 128) {
    int l0 = lb[t], l1 = lb[t + 1];
    float m0 = (float)mask_s[t], m1 = (float)mask_s[t + 1];
    spart += trans[l0 * Tc + l1] * m1 + xb[t * Tc + l0] * m0;
  }
  __syncthreads();
  sred[j] = spart;
  __syncthreads();
#pragma unroll
  for (int s = 64; s > 0; s >>= 1) {
    if (j < s) sred[j] += sred[j + s];
    __syncthreads();
  }
  if (j == 0) {
    int last_idx = msum - 1;
    int lt = lb[last_idx];
    s_score = sred[0] + startT[lb[0]] + endT[lt]
            + xb[(Lc - 1) * Tc + lt] * (float)mask_s[Lc - 1];
  }

  // ---- forward recurrence ----
  float a = startT[j] + xb[j];        // alpha_0[j]
  if (j == 0) mslot = a;
  float x0 = xb[1 * Tc + j];          // emit prefetch, 2 steps deep
  float x1 = xb[2 * Tc + j];
  __syncthreads();                    // publishes mslot + s_score

  for (int t = 1; t < Lc; ++t) {
    int tpre = (t + 2 < Lc) ? (t + 2) : (Lc - 1);
    float x2 = xb[tpre * Tc + j];     // stays in flight across raw barriers
    int mt = mask_s[t];
    float m = mslot;                  // shift = alpha_{t-1}[0] (exact lse shift)
    float pj = __expf(a - m);
    p[j] = pj;
    bar_lgkm();

    const float4* P4 = (const float4*)p;
    float acc0 = 0.f, acc1 = 0.f, acc2 = 0.f, acc3 = 0.f;
#pragma unroll
    for (int i = 0; i < Tc / 4; i += 4) {
      float4 p0 = P4[i + 0], p1 = P4[i + 1], p2 = P4[i + 2], p3 = P4[i + 3];
      acc0 = fmaf(ecol[i + 0].x, p0.x, acc0);
      acc0 = fmaf(ecol[i + 0].y, p0.y, acc0);
      acc0 = fmaf(ecol[i + 0].z, p0.z, acc0);
      acc0 = fmaf(ecol[i + 0].w, p0.w, acc0);
      acc1 = fmaf(ecol[i + 1].x, p1.x, acc1);
      acc1 = fmaf(ecol[i + 1].y, p1.y, acc1);
      acc1 = fmaf(ecol[i + 1].z, p1.z, acc1);
      acc1 = fmaf(ecol[i + 1].w, p1.w, acc1);
      acc2 = fmaf(ecol[i + 2].x, p2.x, acc2);
      acc2 = fmaf(ecol[i + 2].y, p2.y, acc2);
      acc2 = fmaf(ecol[i + 2].z, p2.z, acc2);
      acc2 = fmaf(ecol[i + 2].w, p2.w, acc2);
      acc3 = fmaf(ecol[i + 3].x, p3.x, acc3);
      acc3 = fmaf(ecol[i + 3].y, p3.y, acc3);
      acc3 = fmaf(ecol[i + 3].z, p3.z, acc3);
      acc3 = fmaf(ecol[i + 3].w, p3.w, acc3);
    }
    float acc = (acc0 + acc1) + (acc2 + acc3);
    float na = x0 + m + __logf(acc);
    a = mt ? na : a;                  // mask blend (mask in {0,1})
    x0 = x1; x1 = x2;
    if (j == 0) mslot = a;            // publish shift for next step
    bar_lgkm();
  }

  // ---- log_denominator = logsumexp_j(alpha + end) ----
  float v = a + endT[j];
  float wm = v;
#pragma unroll
  for (int off = 32; off; off >>= 1) wm = fmaxf(wm, __shfl_xor(wm, off));
  if (lane == 0) sred[wid] = wm;
  __syncthreads();
  float M = fmaxf(sred[0], sred[1]);
  float e = __expf(v - M);
  float wsum = e;
#pragma unroll
  for (int off = 32; off; off >>= 1) wsum += __shfl_xor(wsum, off);
  if (lane == 0) sred[2 + wid] = wsum;
  __syncthreads();
  if (j == 0) {
    float ld = M + __logf(sred[2] + sred[3]);
    diff_out[b] = ld - s_score;
    msum_out[b] = (float)msum;
  }
}

__global__ __launch_bounds__(512)
void crf_final(const float* __restrict__ diff, const float* __restrict__ msum,
               float* __restrict__ out)
{
  __shared__ float sd[512];
  __shared__ float sm[512];
  int t = threadIdx.x;
  sd[t] = diff[t];
  sm[t] = msum[t];
  __syncthreads();
  for (int s = 256; s > 0; s >>= 1) {
    if (t < s) { sd[t] += sd[t + s]; sm[t] += sm[t + s]; }
    __syncthreads();
  }
  if (t == 0) out[0] = sd[0] / sm[0];
}

extern "C" void kernel_launch(void* const* d_in, const int* in_sizes, int n_in,
                              void* d_out, int out_size, void* d_ws, size_t ws_size,
                              hipStream_t stream) {
  const float* x      = (const float*)d_in[0];
  const float* trans  = (const float*)d_in[1];
  const float* startT = (const float*)d_in[2];
  const float* endT   = (const float*)d_in[3];
  const int*   labels = (const int*)d_in[4];
  const int*   mask   = (const int*)d_in[5];
  float* out = (float*)d_out;
  float* ws  = (float*)d_ws;
  float* diff = ws;        // [512]
  float* msum = ws + Bc;   // [512]

  crf_forward<<<dim3(Bc), dim3(128), 0, stream>>>(
      x, trans, startT, endT, labels, mask, diff, msum);
  crf_final<<<dim3(1), dim3(512), 0, stream>>>(diff, msum, out);
}